// Round 1
// baseline (9078.986 us; speedup 1.0000x reference)
//
#include <hip/hip_runtime.h>

#define BATCH 4
#define NPOS 4096         // H*W
#define CCH  256          // channels
#define MTOT (BATCH*NPOS) // 16384

// ---------------------------------------------------------------------------
// ws layout (floats):
//   xw1 : [0,   P)      P = MTOT*CCH = 4194304
//   xw2 : [P,  2P)
//   xw3 : [2P, 3P)
//   gw1 : [3P, 4P)
//   gw2 : [4P, 5P)
//   stats at 5P: c_[MTOT], invD[MTOT], m2[MTOT], invZ2[MTOT]
// total = 5P + 4*MTOT floats ~= 84.1 MB
// ---------------------------------------------------------------------------

__device__ __forceinline__ float wred_max(float v) {
#pragma unroll
    for (int o = 32; o >= 1; o >>= 1) v = fmaxf(v, __shfl_xor(v, o, 64));
    return v;
}
__device__ __forceinline__ float wred_sum(float v) {
#pragma unroll
    for (int o = 32; o >= 1; o >>= 1) v += __shfl_xor(v, o, 64);
    return v;
}

// ---------------------------------------------------------------------------
// K1: 5 projections  out[m][n] = sum_k A[m][k]*W[k][n] + b[n]
// grid (M/32, C/32, 5), block 256
// ---------------------------------------------------------------------------
__global__ __launch_bounds__(256) void proj_kernel(
    const float* __restrict__ x, const float* __restrict__ g,
    const float* __restrict__ Wx1, const float* __restrict__ bx1,
    const float* __restrict__ Wx2, const float* __restrict__ bx2,
    const float* __restrict__ Wx3, const float* __restrict__ bx3,
    const float* __restrict__ Wg1, const float* __restrict__ bg1,
    const float* __restrict__ Wg2, const float* __restrict__ bg2,
    float* __restrict__ ws)
{
    const size_t P = (size_t)MTOT * CCH;
    const int p = blockIdx.z;
    const float* A = (p < 3) ? x : g;
    const float* W; const float* bias; float* out;
    switch (p) {
        case 0:  W = Wx1; bias = bx1; out = ws;         break;
        case 1:  W = Wx2; bias = bx2; out = ws + P;     break;
        case 2:  W = Wx3; bias = bx3; out = ws + 2*P;   break;
        case 3:  W = Wg1; bias = bg1; out = ws + 3*P;   break;
        default: W = Wg2; bias = bg2; out = ws + 4*P;   break;
    }

    __shared__ float As[32][33];   // [m][k], padded (scalar broadcast reads)
    __shared__ float Ws_[32][32];  // [k][n], unpadded (float4 reads)

    const int t = threadIdx.x;
    const int m0 = blockIdx.x * 32;
    const int n0 = blockIdx.y * 32;
    const int r  = t >> 3;         // 0..31 row in tile
    const int cg = t & 7;          // col group (4 cols)
    const int lrow = t >> 3;
    const int lcol = (t & 7) << 2;

    float acc[4] = {0.f, 0.f, 0.f, 0.f};

    for (int k0 = 0; k0 < CCH; k0 += 32) {
        float4 av = *(const float4*)&A[(size_t)(m0 + lrow) * CCH + k0 + lcol];
        As[lrow][lcol+0] = av.x; As[lrow][lcol+1] = av.y;
        As[lrow][lcol+2] = av.z; As[lrow][lcol+3] = av.w;
        float4 wv = *(const float4*)&W[(size_t)(k0 + lrow) * CCH + n0 + lcol];
        *(float4*)&Ws_[lrow][lcol] = wv;
        __syncthreads();
#pragma unroll
        for (int kk = 0; kk < 32; ++kk) {
            const float a = As[r][kk];
            const float4 w4 = *(const float4*)&Ws_[kk][cg << 2];
            acc[0] = fmaf(a, w4.x, acc[0]);
            acc[1] = fmaf(a, w4.y, acc[1]);
            acc[2] = fmaf(a, w4.z, acc[2]);
            acc[3] = fmaf(a, w4.w, acc[3]);
        }
        __syncthreads();
    }
#pragma unroll
    for (int q = 0; q < 4; ++q)
        out[(size_t)(m0 + r) * CCH + n0 + (cg << 2) + q] = acc[q] + bias[n0 + (cg << 2) + q];
}

// ---------------------------------------------------------------------------
// S-tile helper for stats kernel: computes Sx,Sg for a [32 i] x [256 j] tile.
// Thread map: wave = ig (8 rows i each), lane jg (4 cols j each).
// ---------------------------------------------------------------------------
__device__ __forceinline__ void compute_S_tile(
    const float* __restrict__ Ax, const float* __restrict__ Ag,
    const float* __restrict__ Bx, const float* __restrict__ Bg,
    int i0, int j0, int t,
    float (*ax_t)[32], float (*ag_t)[32],
    float (*bx_t)[256], float (*bg_t)[256],
    float (&sx)[8][4], float (&sg)[8][4])
{
    const int ig = t >> 6;
    const int jg = t & 63;
#pragma unroll
    for (int ii = 0; ii < 8; ++ii)
#pragma unroll
        for (int q = 0; q < 4; ++q) { sx[ii][q] = 0.f; sg[ii][q] = 0.f; }

    const int arow = t >> 3;          // 0..31
    const int acol = (t & 7) << 2;    // 0..28

    for (int k0 = 0; k0 < CCH; k0 += 32) {
        float4 v;
        // stage A chunks transposed: [k][i]
        v = *(const float4*)&Ax[(size_t)(i0 + arow) * CCH + k0 + acol];
        ax_t[acol+0][arow] = v.x; ax_t[acol+1][arow] = v.y;
        ax_t[acol+2][arow] = v.z; ax_t[acol+3][arow] = v.w;
        v = *(const float4*)&Ag[(size_t)(i0 + arow) * CCH + k0 + acol];
        ag_t[acol+0][arow] = v.x; ag_t[acol+1][arow] = v.y;
        ag_t[acol+2][arow] = v.z; ag_t[acol+3][arow] = v.w;
        // stage B chunks transposed: [k][j], 256 rows x 32 k
#pragma unroll
        for (int rep = 0; rep < 8; ++rep) {
            const int e = t + rep * 256;
            const int brow = e >> 3;          // 0..255
            const int bcol = (e & 7) << 2;
            v = *(const float4*)&Bx[(size_t)(j0 + brow) * CCH + k0 + bcol];
            bx_t[bcol+0][brow] = v.x; bx_t[bcol+1][brow] = v.y;
            bx_t[bcol+2][brow] = v.z; bx_t[bcol+3][brow] = v.w;
            v = *(const float4*)&Bg[(size_t)(j0 + brow) * CCH + k0 + bcol];
            bg_t[bcol+0][brow] = v.x; bg_t[bcol+1][brow] = v.y;
            bg_t[bcol+2][brow] = v.z; bg_t[bcol+3][brow] = v.w;
        }
        __syncthreads();
#pragma unroll
        for (int kk = 0; kk < 32; ++kk) {
            const float4 a0 = *(const float4*)&ax_t[kk][ig * 8];
            const float4 a1 = *(const float4*)&ax_t[kk][ig * 8 + 4];
            const float4 g0 = *(const float4*)&ag_t[kk][ig * 8];
            const float4 g1 = *(const float4*)&ag_t[kk][ig * 8 + 4];
            const float4 bxv = *(const float4*)&bx_t[kk][jg * 4];
            const float4 bgv = *(const float4*)&bg_t[kk][jg * 4];
            const float axv[8] = {a0.x,a0.y,a0.z,a0.w,a1.x,a1.y,a1.z,a1.w};
            const float agv[8] = {g0.x,g0.y,g0.z,g0.w,g1.x,g1.y,g1.z,g1.w};
            const float bxa[4] = {bxv.x,bxv.y,bxv.z,bxv.w};
            const float bga[4] = {bgv.x,bgv.y,bgv.z,bgv.w};
#pragma unroll
            for (int ii = 0; ii < 8; ++ii)
#pragma unroll
                for (int q = 0; q < 4; ++q) {
                    sx[ii][q] = fmaf(axv[ii], bxa[q], sx[ii][q]);
                    sg[ii][q] = fmaf(agv[ii], bga[q], sg[ii][q]);
                }
        }
        __syncthreads();
    }
}

// ---------------------------------------------------------------------------
// K2: per-row stats. grid (N/32, B), block 256.
// Pass A: online (mx,Zx), (mg,Zg), Tmax over all j.
// Pass B: Z2 = sum_j exp(v_ij - m2_i), v = exp(T - c)*invD.
// ---------------------------------------------------------------------------
__global__ __launch_bounds__(256) void stats_kernel(float* __restrict__ ws)
{
    const size_t P = (size_t)MTOT * CCH;
    const int b  = blockIdx.y;
    const int i0 = blockIdx.x * 32;
    const size_t boff = (size_t)b * NPOS * CCH;
    const float* xw1 = ws + boff;
    const float* xw2 = ws + P + boff;
    const float* gw1 = ws + 3 * P + boff;
    const float* gw2 = ws + 4 * P + boff;
    float* st = ws + 5 * P;

    __shared__ float ax_t[32][32], ag_t[32][32];
    __shared__ float bx_t[32][256], bg_t[32][256];

    const int t  = threadIdx.x;
    const int ig = t >> 6;

    float mx[8], Zx[8], mg[8], Zg[8], Tm[8];
#pragma unroll
    for (int ii = 0; ii < 8; ++ii) {
        mx[ii] = -3e38f; mg[ii] = -3e38f; Tm[ii] = -3e38f;
        Zx[ii] = 0.f; Zg[ii] = 0.f;
    }
    float sx[8][4], sg[8][4];

    // ---- pass A ----
    for (int jt = 0; jt < 16; ++jt) {
        compute_S_tile(xw2, gw2, xw1, gw1, i0, jt * 256, t, ax_t, ag_t, bx_t, bg_t, sx, sg);
#pragma unroll
        for (int ii = 0; ii < 8; ++ii) {
            // x branch
            float lm = fmaxf(fmaxf(sx[ii][0], sx[ii][1]), fmaxf(sx[ii][2], sx[ii][3]));
            float tm = wred_max(lm);
            float nm = fmaxf(mx[ii], tm);
            float ls = 0.f;
#pragma unroll
            for (int q = 0; q < 4; ++q) ls += __expf(sx[ii][q] - nm);
            ls = wred_sum(ls);
            Zx[ii] = Zx[ii] * __expf(mx[ii] - nm) + ls;
            mx[ii] = nm;
            // g branch
            lm = fmaxf(fmaxf(sg[ii][0], sg[ii][1]), fmaxf(sg[ii][2], sg[ii][3]));
            tm = wred_max(lm);
            nm = fmaxf(mg[ii], tm);
            ls = 0.f;
#pragma unroll
            for (int q = 0; q < 4; ++q) ls += __expf(sg[ii][q] - nm);
            ls = wred_sum(ls);
            Zg[ii] = Zg[ii] * __expf(mg[ii] - nm) + ls;
            mg[ii] = nm;
            // Tmax
            lm = sx[ii][0] + sg[ii][0];
            lm = fmaxf(lm, sx[ii][1] + sg[ii][1]);
            lm = fmaxf(lm, sx[ii][2] + sg[ii][2]);
            lm = fmaxf(lm, sx[ii][3] + sg[ii][3]);
            tm = wred_max(lm);
            Tm[ii] = fmaxf(Tm[ii], tm);
        }
    }

    float cc[8], iD[8], mm2[8], z2[8];
#pragma unroll
    for (int ii = 0; ii < 8; ++ii) {
        cc[ii]  = mx[ii] + mg[ii];
        iD[ii]  = 1.f / (Zx[ii] * Zg[ii]);
        mm2[ii] = __expf(Tm[ii] - cc[ii]) * iD[ii];   // Tm <= cc, so in (0,1]
        z2[ii]  = 0.f;
    }

    // ---- pass B ----
    for (int jt = 0; jt < 16; ++jt) {
        compute_S_tile(xw2, gw2, xw1, gw1, i0, jt * 256, t, ax_t, ag_t, bx_t, bg_t, sx, sg);
#pragma unroll
        for (int ii = 0; ii < 8; ++ii)
#pragma unroll
            for (int q = 0; q < 4; ++q) {
                const float w = __expf(sx[ii][q] + sg[ii][q] - cc[ii]) * iD[ii];
                z2[ii] += __expf(w - mm2[ii]);
            }
    }
#pragma unroll
    for (int ii = 0; ii < 8; ++ii) z2[ii] = wred_sum(z2[ii]);

    if ((t & 63) == 0) {
#pragma unroll
        for (int ii = 0; ii < 8; ++ii) {
            const int gi = b * NPOS + i0 + ig * 8 + ii;
            st[gi]            = cc[ii];
            st[MTOT + gi]     = iD[ii];
            st[2 * MTOT + gi] = mm2[ii];
            st[3 * MTOT + gi] = 1.f / z2[ii];
        }
    }
}

// ---------------------------------------------------------------------------
// K3: output. grid (N/64, B), block 256. Each block owns 64 output rows j,
// loops i-tiles of 32: recompute T, form attn, accumulate attn^T @ xw3.
// out = x + acc.
// ---------------------------------------------------------------------------
__global__ __launch_bounds__(256) void out_kernel(
    const float* __restrict__ x, float* __restrict__ ws, float* __restrict__ out)
{
    const size_t P = (size_t)MTOT * CCH;
    const int b  = blockIdx.y;
    const int j0 = blockIdx.x * 64;
    const size_t boff = (size_t)b * NPOS * CCH;
    const float* xw1 = ws + boff;
    const float* xw2 = ws + P + boff;
    const float* xw3 = ws + 2 * P + boff;
    const float* gw1 = ws + 3 * P + boff;
    const float* gw2 = ws + 4 * P + boff;
    const float* st  = ws + 5 * P;

    __shared__ float axk[32][32], agk[32][32];   // [k][i]
    __shared__ float bxk[32][64], bgk[32][64];   // [k][j]
    __shared__ float attn_t[32][65];             // [i][j] padded
    __shared__ float xw3_t[32][256];             // [i][c]

    const int t   = threadIdx.x;
    const int tig = t >> 5;          // 0..7 -> i rows tig*4..+3
    const int tjg = t & 31;          // 0..31 -> j cols tjg*2, +1
    const int jl  = t >> 2;          // 0..63 output row in tile
    const int c0  = (t & 3) << 6;    // 0,64,128,192

    float outr[64];
#pragma unroll
    for (int s = 0; s < 64; ++s) outr[s] = 0.f;

    const int arow = t >> 3;
    const int acol = (t & 7) << 2;

    for (int it = 0; it < 128; ++it) {
        const int i0 = it * 32;
        float tsx[4][2] = {{0.f,0.f},{0.f,0.f},{0.f,0.f},{0.f,0.f}};
        float tsg[4][2] = {{0.f,0.f},{0.f,0.f},{0.f,0.f},{0.f,0.f}};

        for (int k0 = 0; k0 < CCH; k0 += 32) {
            float4 v;
            v = *(const float4*)&xw2[(size_t)(i0 + arow) * CCH + k0 + acol];
            axk[acol+0][arow] = v.x; axk[acol+1][arow] = v.y;
            axk[acol+2][arow] = v.z; axk[acol+3][arow] = v.w;
            v = *(const float4*)&gw2[(size_t)(i0 + arow) * CCH + k0 + acol];
            agk[acol+0][arow] = v.x; agk[acol+1][arow] = v.y;
            agk[acol+2][arow] = v.z; agk[acol+3][arow] = v.w;
#pragma unroll
            for (int rep = 0; rep < 2; ++rep) {
                const int e = t + rep * 256;
                const int brow = e >> 3;         // 0..63
                const int bcol = (e & 7) << 2;
                v = *(const float4*)&xw1[(size_t)(j0 + brow) * CCH + k0 + bcol];
                bxk[bcol+0][brow] = v.x; bxk[bcol+1][brow] = v.y;
                bxk[bcol+2][brow] = v.z; bxk[bcol+3][brow] = v.w;
                v = *(const float4*)&gw1[(size_t)(j0 + brow) * CCH + k0 + bcol];
                bgk[bcol+0][brow] = v.x; bgk[bcol+1][brow] = v.y;
                bgk[bcol+2][brow] = v.z; bgk[bcol+3][brow] = v.w;
            }
            __syncthreads();
#pragma unroll
            for (int kk = 0; kk < 32; ++kk) {
                const float4 a_x = *(const float4*)&axk[kk][tig * 4];
                const float4 a_g = *(const float4*)&agk[kk][tig * 4];
                const float2 b_x = *(const float2*)&bxk[kk][tjg * 2];
                const float2 b_g = *(const float2*)&bgk[kk][tjg * 2];
                const float axv[4] = {a_x.x, a_x.y, a_x.z, a_x.w};
                const float agv[4] = {a_g.x, a_g.y, a_g.z, a_g.w};
                const float bxv[2] = {b_x.x, b_x.y};
                const float bgv[2] = {b_g.x, b_g.y};
#pragma unroll
                for (int ii = 0; ii < 4; ++ii)
#pragma unroll
                    for (int jj = 0; jj < 2; ++jj) {
                        tsx[ii][jj] = fmaf(axv[ii], bxv[jj], tsx[ii][jj]);
                        tsg[ii][jj] = fmaf(agv[ii], bgv[jj], tsg[ii][jj]);
                    }
            }
            __syncthreads();
        }

        // attn for this i-tile
#pragma unroll
        for (int ii = 0; ii < 4; ++ii) {
            const int gi = b * NPOS + i0 + tig * 4 + ii;
            const float ccv = st[gi];
            const float iDv = st[MTOT + gi];
            const float mmv = st[2 * MTOT + gi];
            const float iZv = st[3 * MTOT + gi];
#pragma unroll
            for (int jj = 0; jj < 2; ++jj) {
                const float w = __expf(tsx[ii][jj] + tsg[ii][jj] - ccv) * iDv;
                attn_t[tig * 4 + ii][tjg * 2 + jj] = __expf(w - mmv) * iZv;
            }
        }
        // stage xw3 tile [32][256]
#pragma unroll
        for (int rep = 0; rep < 8; ++rep) {
            const int e = t + rep * 256;
            const int row = e >> 6;            // 0..31
            const int col = (e & 63) << 2;     // 0..252
            *(float4*)&xw3_t[row][col] = *(const float4*)&xw3[(size_t)(i0 + row) * CCH + col];
        }
        __syncthreads();

        // PV: outr[j=jl, c0..c0+63] += sum_ii attn[ii][jl] * xw3[ii][c]
#pragma unroll 4
        for (int ii = 0; ii < 32; ++ii) {
            const float a = attn_t[ii][jl];
#pragma unroll
            for (int s4 = 0; s4 < 16; ++s4) {
                const float4 v = *(const float4*)&xw3_t[ii][c0 + s4 * 4];
                outr[s4*4+0] = fmaf(a, v.x, outr[s4*4+0]);
                outr[s4*4+1] = fmaf(a, v.y, outr[s4*4+1]);
                outr[s4*4+2] = fmaf(a, v.z, outr[s4*4+2]);
                outr[s4*4+3] = fmaf(a, v.w, outr[s4*4+3]);
            }
        }
        __syncthreads();
    }

    const size_t ob = ((size_t)b * NPOS + j0 + jl) * CCH + c0;
#pragma unroll
    for (int s4 = 0; s4 < 16; ++s4) {
        float4 xv = *(const float4*)&x[ob + s4 * 4];
        float4 r;
        r.x = xv.x + outr[s4*4+0];
        r.y = xv.y + outr[s4*4+1];
        r.z = xv.z + outr[s4*4+2];
        r.w = xv.w + outr[s4*4+3];
        *(float4*)&out[ob + s4 * 4] = r;
    }
}

extern "C" void kernel_launch(void* const* d_in, const int* in_sizes, int n_in,
                              void* d_out, int out_size, void* d_ws, size_t ws_size,
                              hipStream_t stream)
{
    const float* x = (const float*)d_in[0];
    const float* g = (const float*)d_in[1];
    float* ws  = (float*)d_ws;
    float* out = (float*)d_out;

    dim3 blk(256);
    proj_kernel<<<dim3(MTOT / 32, CCH / 32, 5), blk, 0, stream>>>(
        x, g,
        (const float*)d_in[2],  (const float*)d_in[3],
        (const float*)d_in[4],  (const float*)d_in[5],
        (const float*)d_in[6],  (const float*)d_in[7],
        (const float*)d_in[8],  (const float*)d_in[9],
        (const float*)d_in[10], (const float*)d_in[11],
        ws);
    stats_kernel<<<dim3(NPOS / 32, BATCH), blk, 0, stream>>>(ws);
    out_kernel<<<dim3(NPOS / 64, BATCH), blk, 0, stream>>>(x, ws, out);
}

// Round 2
// 661.103 us; speedup vs baseline: 13.7331x; 13.7331x over previous
//
#include <hip/hip_runtime.h>

typedef float f32x4 __attribute__((ext_vector_type(4)));
typedef short s16x8 __attribute__((ext_vector_type(8)));
typedef unsigned char u8;
typedef unsigned short u16;
typedef unsigned int u32;

#define NPOS 4096
#define CCH  256
#define MTOT 16384

// ---- ws layout (bytes) ----
#define SZ_F8   ((size_t)MTOT * 256)               // one fp8 projection: 4 MB
#define O_F8    ((size_t)0)                        // [4] x fp8 [16384][256]: xw1,xw2,gw1,gw2
#define O_WT    (O_F8   + 4 * SZ_F8)               // bf16 [5][256][256]
#define O_XW3T  (O_WT   + (size_t)5*256*256*2)     // bf16 [4][256][4096]
#define O_XW3S  (O_XW3T + (size_t)MTOT*256*2)      // bf16 [4][256][4096]
#define O_ZX    (O_XW3S + (size_t)MTOT*256*2)      // f32 [2][16384]
#define O_ZG    (O_ZX   + (size_t)2*MTOT*4)
#define O_ID    (O_ZG   + (size_t)2*MTOT*4)        // f32 [16384]
#define O_Z2    (O_ID   + (size_t)MTOT*4)          // f32 [4][16384]
#define O_IZ2   (O_Z2   + (size_t)4*MTOT*4)        // f32 [16384]
#define O_P     (O_IZ2  + (size_t)MTOT*4)          // bf16 [4096][4096] (per-batch reuse)

__device__ __forceinline__ u16 f2bf(float f) {
    u32 u = __builtin_bit_cast(u32, f);
    u32 r = (u + 0x7FFFu + ((u >> 16) & 1u)) >> 16;
    return (u16)r;
}
__device__ __forceinline__ float bf2f(u16 h) {
    u32 u = ((u32)h) << 16;
    return __builtin_bit_cast(float, u);
}
__device__ __forceinline__ f32x4 mfma_bf16(s16x8 a, s16x8 b, f32x4 c) {
    return __builtin_amdgcn_mfma_f32_16x16x32_bf16(a, b, c, 0, 0, 0);
}
__device__ __forceinline__ f32x4 mfma_fp8(long a, long b, f32x4 c) {
    return __builtin_amdgcn_mfma_f32_16x16x32_fp8_fp8(a, b, c, 0, 0, 0);
}

// ---------------------------------------------------------------------------
// prep_w: W[k][n] fp32 -> W_T[p][n][k] bf16.  grid (5,4), block 256 (t = n).
// ---------------------------------------------------------------------------
__global__ __launch_bounds__(256) void prep_w(
    const float* __restrict__ W0, const float* __restrict__ W1,
    const float* __restrict__ W2, const float* __restrict__ W3,
    const float* __restrict__ W4, u32* __restrict__ wT)
{
    const int p = blockIdx.x, kq = blockIdx.y, n = threadIdx.x;
    const float* W = (p==0)?W0:(p==1)?W1:(p==2)?W2:(p==3)?W3:W4;
#pragma unroll 4
    for (int kk = 0; kk < 32; ++kk) {
        int k = kq*64 + kk*2;
        float v0 = W[k*256 + n];
        float v1 = W[(k+1)*256 + n];
        wT[(p*65536 + n*256 + k) >> 1] = (u32)f2bf(v0) | ((u32)f2bf(v1) << 16);
    }
}

// ---------------------------------------------------------------------------
// proj: 5 projections with bf16 MFMA. grid (128, 2), block 256 (4 waves 2x2).
// Block tile 128m x 256n, K=256. Outputs: fp8 row-major (xw1,xw2,gw1,gw2),
// bf16 transposed xw3T[b][c][pos] for p==2.
// ---------------------------------------------------------------------------
__global__ __launch_bounds__(256) void proj_kernel(
    const float* __restrict__ x, const float* __restrict__ g,
    const float* __restrict__ bb0, const float* __restrict__ bb1,
    const float* __restrict__ bb2, const float* __restrict__ bb3,
    const float* __restrict__ bb4,
    const u16* __restrict__ wT, u8* __restrict__ f8, u8* __restrict__ xw3T)
{
    const int branch = blockIdx.y;
    const int m0 = blockIdx.x * 128;
    const float* A = branch ? g : x;
    __shared__ u8 sA[128*512];   // bf16 [128 m][256 k], XOR-swizzled
    __shared__ u8 sC[128*512];   // bf16 bounce [128 m][256 n], XOR-swizzled
    const int t = threadIdx.x;
    const int l = t & 63, lr = l & 15, lg = l >> 4;
    const int wv = t >> 6, wm = wv >> 1, wn = wv & 1;

    { // stage A -> bf16 LDS (swizzled)
        const int m = t >> 1, h = t & 1;
        const float* src = &A[(size_t)(m0 + m) * 256 + h * 128];
        const u32 dbase = m * 512;
#pragma unroll
        for (int c = 0; c < 16; ++c) {
            float4 a = *(const float4*)(src + c*8);
            float4 b = *(const float4*)(src + c*8 + 4);
            u32 pk[4] = { (u32)f2bf(a.x) | ((u32)f2bf(a.y)<<16),
                          (u32)f2bf(a.z) | ((u32)f2bf(a.w)<<16),
                          (u32)f2bf(b.x) | ((u32)f2bf(b.y)<<16),
                          (u32)f2bf(b.z) | ((u32)f2bf(b.w)<<16) };
            int kbyte = h*256 + c*16;
            *(uint4*)&sA[dbase + (kbyte ^ ((m & 7) << 4))] = *(uint4*)pk;
        }
    }
    __syncthreads();

    const int np = branch ? 2 : 3;
    for (int pp = 0; pp < np; ++pp) {
        const int p = branch ? 3 + pp : pp;
        const float* bias = (p==0)?bb0:(p==1)?bb1:(p==2)?bb2:(p==3)?bb3:bb4;
        f32x4 acc[4][8];
#pragma unroll
        for (int i = 0; i < 4; ++i)
#pragma unroll
            for (int j = 0; j < 8; ++j) acc[i][j] = (f32x4){0.f,0.f,0.f,0.f};

#pragma unroll
        for (int ks = 0; ks < 8; ++ks) {
            s16x8 af[4];
#pragma unroll
            for (int Mt = 0; Mt < 4; ++Mt) {
                int m = wm*64 + Mt*16 + lr;
                af[Mt] = *(const s16x8*)&sA[m*512 + ((ks*64 + lg*16) ^ ((m & 7) << 4))];
            }
#pragma unroll
            for (int Nt = 0; Nt < 8; ++Nt) {
                int n = wn*128 + Nt*16 + lr;
                s16x8 bf = *(const s16x8*)&wT[p*65536 + n*256 + ks*32 + lg*8];
#pragma unroll
                for (int Mt = 0; Mt < 4; ++Mt)
                    acc[Mt][Nt] = mfma_bf16(af[Mt], bf, acc[Mt][Nt]);
            }
        }
        // bias
#pragma unroll
        for (int Nt = 0; Nt < 8; ++Nt) {
            float bv = bias[wn*128 + Nt*16 + lr];
#pragma unroll
            for (int Mt = 0; Mt < 4; ++Mt)
#pragma unroll
                for (int q = 0; q < 4; ++q) acc[Mt][Nt][q] += bv;
        }

        if (p == 2) { // xw3T[b][n][pos] bf16, direct transposed stores
#pragma unroll
            for (int Mt = 0; Mt < 4; ++Mt)
#pragma unroll
                for (int Nt = 0; Nt < 8; ++Nt) {
                    int n = wn*128 + Nt*16 + lr;
                    int mrow = m0 + wm*64 + Mt*16 + lg*4;
                    int bb = mrow >> 12, pos = mrow & 4095;
                    uint2 val;
                    val.x = (u32)f2bf(acc[Mt][Nt][0]) | ((u32)f2bf(acc[Mt][Nt][1]) << 16);
                    val.y = (u32)f2bf(acc[Mt][Nt][2]) | ((u32)f2bf(acc[Mt][Nt][3]) << 16);
                    *(uint2*)(xw3T + ((size_t)(bb*256 + n)*4096 + pos)*2) = val;
                }
        } else {
            const int fi = (p < 2) ? p : p - 1;  // 0:xw1 1:xw2 2:gw1 3:gw2
#pragma unroll
            for (int Mt = 0; Mt < 4; ++Mt)
#pragma unroll
                for (int Nt = 0; Nt < 8; ++Nt) {
                    int n = wn*128 + Nt*16 + lr;
#pragma unroll
                    for (int q = 0; q < 4; ++q) {
                        int m = wm*64 + Mt*16 + lg*4 + q;
                        *(u16*)&sC[m*512 + ((n*2) ^ ((m & 7) << 4))] = f2bf(acc[Mt][Nt][q]);
                    }
                }
            __syncthreads();
            { // coalesced fp8 write-out
                const int m = t >> 1, h = t & 1;
                u8* dst = f8 + (size_t)fi * SZ_F8 + (size_t)(m0 + m)*256 + h*128;
#pragma unroll
                for (int c = 0; c < 16; ++c) {
                    uint4 v = *(const uint4*)&sC[m*512 + ((h*256 + c*16) ^ ((m & 7) << 4))];
                    float fv[8] = { bf2f((u16)(v.x & 0xffff)), bf2f((u16)(v.x >> 16)),
                                    bf2f((u16)(v.y & 0xffff)), bf2f((u16)(v.y >> 16)),
                                    bf2f((u16)(v.z & 0xffff)), bf2f((u16)(v.z >> 16)),
                                    bf2f((u16)(v.w & 0xffff)), bf2f((u16)(v.w >> 16)) };
                    u32 o0 = 0, o1 = 0;
                    o0 = __builtin_amdgcn_cvt_pk_fp8_f32(fv[0], fv[1], o0, false);
                    o0 = __builtin_amdgcn_cvt_pk_fp8_f32(fv[2], fv[3], o0, true);
                    o1 = __builtin_amdgcn_cvt_pk_fp8_f32(fv[4], fv[5], o1, false);
                    o1 = __builtin_amdgcn_cvt_pk_fp8_f32(fv[6], fv[7], o1, true);
                    uint2 ov; ov.x = o0; ov.y = o1;
                    *(uint2*)(dst + c*8) = ov;
                }
            }
            __syncthreads();
        }
    }
}

// ---------------------------------------------------------------------------
// stats1: Zx[i] = sum_j exp(Sx[i,j]), Zg likewise (no max needed; S bounded).
// grid (32, 2, 4) = (i-block of 128, j-half, batch), block 256 (4 waves).
// Wave holds A-fragments (xw2,gw2 rows, fp8) in registers; B staged in LDS.
// ---------------------------------------------------------------------------
__global__ __launch_bounds__(256) void stats1_kernel(
    const u8* __restrict__ f8, float* __restrict__ ZxP, float* __restrict__ ZgP)
{
    const int iblk = blockIdx.x, js = blockIdx.y, b = blockIdx.z;
    const int i0 = iblk * 128;
    const int t = threadIdx.x, l = t & 63, lr = l & 15, lg = l >> 4, w = t >> 6;
    const u8* Ax = f8 + SZ_F8*1 + ((size_t)(b*NPOS + i0 + w*32))*256;
    const u8* Ag = f8 + SZ_F8*3 + ((size_t)(b*NPOS + i0 + w*32))*256;
    const u8* Bx = f8 + SZ_F8*0 + ((size_t)(b*NPOS))*256;
    const u8* Bg = f8 + SZ_F8*2 + ((size_t)(b*NPOS))*256;

    long ax[2][8], ag[2][8];
#pragma unroll
    for (int Mt = 0; Mt < 2; ++Mt)
#pragma unroll
        for (int ks = 0; ks < 8; ++ks) {
            ax[Mt][ks] = *(const long*)&Ax[(Mt*16 + lr)*256 + ks*32 + lg*8];
            ag[Mt][ks] = *(const long*)&Ag[(Mt*16 + lr)*256 + ks*32 + lg*8];
        }

    float zx[2][4], zg[2][4];
#pragma unroll
    for (int Mt = 0; Mt < 2; ++Mt)
#pragma unroll
        for (int q = 0; q < 4; ++q) { zx[Mt][q] = 0.f; zg[Mt][q] = 0.f; }

    __shared__ u8 sb[16384];
    for (int jc = 0; jc < 64; ++jc) {
        const int j0 = js*2048 + jc*32;
#pragma unroll
        for (int rep = 0; rep < 4; ++rep) {
            int s = rep*256 + t;
            int br = s >> 9, s2 = s & 511;
            int jr = s2 >> 4, kb = (s2 & 15) << 4;
            const u8* src = (br ? Bg : Bx) + (size_t)(j0 + jr)*256 + kb;
            *(uint4*)&sb[br*8192 + jr*256 + (kb ^ ((jr & 7) << 4))] = *(const uint4*)src;
        }
        __syncthreads();
        f32x4 cx[2][2], cg[2][2];
#pragma unroll
        for (int Mt = 0; Mt < 2; ++Mt)
#pragma unroll
            for (int jt = 0; jt < 2; ++jt) { cx[Mt][jt] = (f32x4){0,0,0,0}; cg[Mt][jt] = (f32x4){0,0,0,0}; }
#pragma unroll
        for (int ks = 0; ks < 8; ++ks)
#pragma unroll
            for (int jt = 0; jt < 2; ++jt) {
                int jrow = jt*16 + lr;
                int off = jrow*256 + ((ks*32 + lg*8) ^ ((jrow & 7) << 4));
                long bxv = *(const long*)&sb[off];
                long bgv = *(const long*)&sb[8192 + off];
#pragma unroll
                for (int Mt = 0; Mt < 2; ++Mt) {
                    cx[Mt][jt] = mfma_fp8(ax[Mt][ks], bxv, cx[Mt][jt]);
                    cg[Mt][jt] = mfma_fp8(ag[Mt][ks], bgv, cg[Mt][jt]);
                }
            }
        __syncthreads();
#pragma unroll
        for (int Mt = 0; Mt < 2; ++Mt)
#pragma unroll
            for (int jt = 0; jt < 2; ++jt)
#pragma unroll
                for (int q = 0; q < 4; ++q) {
                    zx[Mt][q] += __expf(cx[Mt][jt][q]);
                    zg[Mt][q] += __expf(cg[Mt][jt][q]);
                }
    }
#pragma unroll
    for (int Mt = 0; Mt < 2; ++Mt)
#pragma unroll
        for (int q = 0; q < 4; ++q)
#pragma unroll
            for (int o = 1; o < 16; o <<= 1) {
                zx[Mt][q] += __shfl_xor(zx[Mt][q], o, 64);
                zg[Mt][q] += __shfl_xor(zg[Mt][q], o, 64);
            }
    if (lr == 0) {
#pragma unroll
        for (int Mt = 0; Mt < 2; ++Mt)
#pragma unroll
            for (int q = 0; q < 4; ++q) {
                int gi = b*NPOS + i0 + w*32 + Mt*16 + lg*4 + q;
                ZxP[js*MTOT + gi] = zx[Mt][q];
                ZgP[js*MTOT + gi] = zg[Mt][q];
            }
    }
}

// ---------------------------------------------------------------------------
__global__ __launch_bounds__(256) void merge_d(
    const float* __restrict__ ZxP, const float* __restrict__ ZgP,
    float* __restrict__ iD)
{
    int gi = blockIdx.x*256 + threadIdx.x;
    float zx = ZxP[gi] + ZxP[MTOT + gi];
    float zg = ZgP[gi] + ZgP[MTOT + gi];
    iD[gi] = 1.0f / (zx * zg);
}

// ---------------------------------------------------------------------------
// stats2: P^T[j][i] = exp( exp(Sx+Sg) * iD_i ) bf16, and z2 partials.
// grid (32, 4) per batch, block 256.
// ---------------------------------------------------------------------------
__global__ __launch_bounds__(256) void stats2_kernel(
    const u8* __restrict__ f8, const float* __restrict__ iD,
    float* __restrict__ z2P, u8* __restrict__ PT, int b)
{
    const int iblk = blockIdx.x, js = blockIdx.y;
    const int i0 = iblk * 128;
    const int t = threadIdx.x, l = t & 63, lr = l & 15, lg = l >> 4, w = t >> 6;
    const u8* Ax = f8 + SZ_F8*1 + ((size_t)(b*NPOS + i0 + w*32))*256;
    const u8* Ag = f8 + SZ_F8*3 + ((size_t)(b*NPOS + i0 + w*32))*256;
    const u8* Bx = f8 + SZ_F8*0 + ((size_t)(b*NPOS))*256;
    const u8* Bg = f8 + SZ_F8*2 + ((size_t)(b*NPOS))*256;

    long ax[2][8], ag[2][8];
#pragma unroll
    for (int Mt = 0; Mt < 2; ++Mt)
#pragma unroll
        for (int ks = 0; ks < 8; ++ks) {
            ax[Mt][ks] = *(const long*)&Ax[(Mt*16 + lr)*256 + ks*32 + lg*8];
            ag[Mt][ks] = *(const long*)&Ag[(Mt*16 + lr)*256 + ks*32 + lg*8];
        }
    f32x4 iDv[2];
#pragma unroll
    for (int Mt = 0; Mt < 2; ++Mt)
        iDv[Mt] = *(const f32x4*)&iD[b*NPOS + i0 + w*32 + Mt*16 + lg*4];

    float z2a[2][4];
#pragma unroll
    for (int Mt = 0; Mt < 2; ++Mt)
#pragma unroll
        for (int q = 0; q < 4; ++q) z2a[Mt][q] = 0.f;

    __shared__ u8 sb[16384];
    for (int jc = 0; jc < 32; ++jc) {
        const int j0 = js*1024 + jc*32;
#pragma unroll
        for (int rep = 0; rep < 4; ++rep) {
            int s = rep*256 + t;
            int br = s >> 9, s2 = s & 511;
            int jr = s2 >> 4, kb = (s2 & 15) << 4;
            const u8* src = (br ? Bg : Bx) + (size_t)(j0 + jr)*256 + kb;
            *(uint4*)&sb[br*8192 + jr*256 + (kb ^ ((jr & 7) << 4))] = *(const uint4*)src;
        }
        __syncthreads();
        f32x4 cx[2][2], cg[2][2];
#pragma unroll
        for (int Mt = 0; Mt < 2; ++Mt)
#pragma unroll
            for (int jt = 0; jt < 2; ++jt) { cx[Mt][jt] = (f32x4){0,0,0,0}; cg[Mt][jt] = (f32x4){0,0,0,0}; }
#pragma unroll
        for (int ks = 0; ks < 8; ++ks)
#pragma unroll
            for (int jt = 0; jt < 2; ++jt) {
                int jrow = jt*16 + lr;
                int off = jrow*256 + ((ks*32 + lg*8) ^ ((jrow & 7) << 4));
                long bxv = *(const long*)&sb[off];
                long bgv = *(const long*)&sb[8192 + off];
#pragma unroll
                for (int Mt = 0; Mt < 2; ++Mt) {
                    cx[Mt][jt] = mfma_fp8(ax[Mt][ks], bxv, cx[Mt][jt]);
                    cg[Mt][jt] = mfma_fp8(ag[Mt][ks], bgv, cg[Mt][jt]);
                }
            }
        __syncthreads();
#pragma unroll
        for (int Mt = 0; Mt < 2; ++Mt)
#pragma unroll
            for (int jt = 0; jt < 2; ++jt) {
                int j = j0 + jt*16 + lr;
                float e[4];
#pragma unroll
                for (int q = 0; q < 4; ++q) {
                    float T = cx[Mt][jt][q] + cg[Mt][jt][q];
                    float v = __expf(T) * iDv[Mt][q];
                    e[q] = __expf(v);
                    z2a[Mt][q] += e[q];
                }
                uint2 val;
                val.x = (u32)f2bf(e[0]) | ((u32)f2bf(e[1]) << 16);
                val.y = (u32)f2bf(e[2]) | ((u32)f2bf(e[3]) << 16);
                *(uint2*)(PT + ((size_t)j*4096 + (i0 + w*32 + Mt*16 + lg*4))*2) = val;
            }
    }
#pragma unroll
    for (int Mt = 0; Mt < 2; ++Mt)
#pragma unroll
        for (int q = 0; q < 4; ++q)
#pragma unroll
            for (int o = 1; o < 16; o <<= 1)
                z2a[Mt][q] += __shfl_xor(z2a[Mt][q], o, 64);
    if (lr == 0) {
#pragma unroll
        for (int Mt = 0; Mt < 2; ++Mt)
#pragma unroll
            for (int q = 0; q < 4; ++q) {
                int gi = b*NPOS + i0 + w*32 + Mt*16 + lg*4 + q;
                z2P[js*MTOT + gi] = z2a[Mt][q];
            }
    }
}

// ---------------------------------------------------------------------------
__global__ __launch_bounds__(256) void prep_iz2(
    const float* __restrict__ z2P, float* __restrict__ iZ2, int b)
{
    int i = blockIdx.x*256 + threadIdx.x;
    int gi = b*NPOS + i;
    iZ2[gi] = 1.0f / (z2P[gi] + z2P[MTOT + gi] + z2P[2*MTOT + gi] + z2P[3*MTOT + gi]);
}

// xw3s[b][c][i] = xw3T[b][c][i] * iZ2[b*4096+i]   (bf16)
__global__ __launch_bounds__(256) void scalev(
    const u8* __restrict__ xw3T, const float* __restrict__ iZ2,
    u8* __restrict__ xw3s, int b)
{
    int e8 = blockIdx.x*256 + threadIdx.x;   // [0, 131072)
    int c = e8 >> 9, ig = e8 & 511;
    int i = ig * 8;
    size_t off = ((size_t)(b*256 + c)*4096 + i)*2;
    uint4 v = *(const uint4*)(xw3T + off);
    f32x4 z0 = *(const f32x4*)&iZ2[b*NPOS + i];
    f32x4 z1 = *(const f32x4*)&iZ2[b*NPOS + i + 4];
    uint4 r;
    r.x = (u32)f2bf(bf2f((u16)(v.x & 0xffff))*z0[0]) | ((u32)f2bf(bf2f((u16)(v.x >> 16))*z0[1]) << 16);
    r.y = (u32)f2bf(bf2f((u16)(v.y & 0xffff))*z0[2]) | ((u32)f2bf(bf2f((u16)(v.y >> 16))*z0[3]) << 16);
    r.z = (u32)f2bf(bf2f((u16)(v.z & 0xffff))*z1[0]) | ((u32)f2bf(bf2f((u16)(v.z >> 16))*z1[1]) << 16);
    r.w = (u32)f2bf(bf2f((u16)(v.w & 0xffff))*z1[2]) | ((u32)f2bf(bf2f((u16)(v.w >> 16))*z1[3]) << 16);
    *(uint4*)(xw3s + off) = r;
}

// ---------------------------------------------------------------------------
// pv: out[b][j][c] = x[b][j][c] + sum_i P^T[j,i] * xw3s[c,i]   (NT bf16 GEMM)
// grid (64, 4) per batch, block 128 (2 waves, wave = 32j x 64c).
// ---------------------------------------------------------------------------
__global__ __launch_bounds__(128) void pv_kernel(
    const u8* __restrict__ PT, const u8* __restrict__ xw3s,
    const float* __restrict__ x, float* __restrict__ out, int b)
{
    const int j0 = blockIdx.x * 64, c0 = blockIdx.y * 64;
    __shared__ u8 sA[8192], sB[8192];   // bf16 [64][64], XOR-swizzled
    const int t = threadIdx.x, l = t & 63, lr = l & 15, lg = l >> 4, w = t >> 6;

    f32x4 acc[2][4];
#pragma unroll
    for (int Mt = 0; Mt < 2; ++Mt)
#pragma unroll
        for (int Nt = 0; Nt < 4; ++Nt) acc[Mt][Nt] = (f32x4){0,0,0,0};

    for (int kt = 0; kt < 64; ++kt) {
        const int k0 = kt * 64;
#pragma unroll
        for (int rep = 0; rep < 8; ++rep) {
            int s = rep*128 + t;
            int buf = s >> 9, s2 = s & 511;
            int r = s2 >> 3, kb = (s2 & 7) << 4;
            const u8* src = buf
                ? xw3s + ((size_t)(b*256 + c0 + r)*4096 + k0)*2 + kb
                : PT   + ((size_t)(j0 + r)*4096 + k0)*2 + kb;
            u8* dst = (buf ? sB : sA) + r*128 + (kb ^ ((r & 7) << 4));
            *(uint4*)dst = *(const uint4*)src;
        }
        __syncthreads();
#pragma unroll
        for (int ks = 0; ks < 2; ++ks) {
            s16x8 af[2];
#pragma unroll
            for (int Mt = 0; Mt < 2; ++Mt) {
                int rr = w*32 + Mt*16 + lr;
                af[Mt] = *(const s16x8*)&sA[rr*128 + ((ks*64 + lg*16) ^ ((rr & 7) << 4))];
            }
#pragma unroll
            for (int Nt = 0; Nt < 4; ++Nt) {
                int rb = Nt*16 + lr;
                s16x8 bf = *(const s16x8*)&sB[rb*128 + ((ks*64 + lg*16) ^ ((rb & 7) << 4))];
#pragma unroll
                for (int Mt = 0; Mt < 2; ++Mt)
                    acc[Mt][Nt] = mfma_bf16(af[Mt], bf, acc[Mt][Nt]);
            }
        }
        __syncthreads();
    }
#pragma unroll
    for (int Mt = 0; Mt < 2; ++Mt)
#pragma unroll
        for (int Nt = 0; Nt < 4; ++Nt)
#pragma unroll
            for (int q = 0; q < 4; ++q) {
                int j = j0 + w*32 + Mt*16 + lg*4 + q;
                int c = c0 + Nt*16 + lr;
                size_t idx = ((size_t)(b*NPOS + j))*256 + c;
                out[idx] = x[idx] + acc[Mt][Nt][q];
            }
}

// ---------------------------------------------------------------------------
extern "C" void kernel_launch(void* const* d_in, const int* in_sizes, int n_in,
                              void* d_out, int out_size, void* d_ws, size_t ws_size,
                              hipStream_t stream)
{
    const float* x = (const float*)d_in[0];
    const float* g = (const float*)d_in[1];
    const float* W[5]  = {(const float*)d_in[2], (const float*)d_in[4], (const float*)d_in[6],
                          (const float*)d_in[8], (const float*)d_in[10]};
    const float* Bi[5] = {(const float*)d_in[3], (const float*)d_in[5], (const float*)d_in[7],
                          (const float*)d_in[9], (const float*)d_in[11]};
    char* ws = (char*)d_ws;
    u8*  f8   = (u8*)(ws + O_F8);
    u16* wT   = (u16*)(ws + O_WT);
    u8*  xw3T = (u8*)(ws + O_XW3T);
    u8*  xw3s = (u8*)(ws + O_XW3S);
    float* ZxP = (float*)(ws + O_ZX);
    float* ZgP = (float*)(ws + O_ZG);
    float* iD  = (float*)(ws + O_ID);
    float* z2P = (float*)(ws + O_Z2);
    float* iZ2 = (float*)(ws + O_IZ2);
    u8*  PT   = (u8*)(ws + O_P);
    float* out = (float*)d_out;

    prep_w<<<dim3(5,4), 256, 0, stream>>>(W[0], W[1], W[2], W[3], W[4], (u32*)wT);
    proj_kernel<<<dim3(128,2), 256, 0, stream>>>(x, g, Bi[0], Bi[1], Bi[2], Bi[3], Bi[4],
                                                 wT, f8, xw3T);
    stats1_kernel<<<dim3(32,2,4), 256, 0, stream>>>(f8, ZxP, ZgP);
    merge_d<<<64, 256, 0, stream>>>(ZxP, ZgP, iD);
    for (int b = 0; b < 4; ++b) {
        stats2_kernel<<<dim3(32,4), 256, 0, stream>>>(f8, iD, z2P, PT, b);
        prep_iz2<<<16, 256, 0, stream>>>(z2P, iZ2, b);
        scalev<<<512, 256, 0, stream>>>(xw3T, iZ2, xw3s, b);
        pv_kernel<<<dim3(64,4), 128, 0, stream>>>(PT, xw3s, x, out, b);
    }
}

// Round 3
// 306.240 us; speedup vs baseline: 29.6466x; 2.1588x over previous
//
#include <hip/hip_runtime.h>

typedef float f32x4 __attribute__((ext_vector_type(4)));
typedef short s16x8 __attribute__((ext_vector_type(8)));
typedef unsigned char u8;
typedef unsigned short u16;
typedef unsigned int u32;
typedef unsigned long long u64;

#define NPOS 4096
#define CCH  256
#define MTOT 16384
#define PBYTES ((size_t)NPOS * NPOS * 2)   // one batch P, bf16

// ---- ws layout (bytes) ----
#define SZ_F8   ((size_t)MTOT * 256)               // one fp8 projection: 4 MB
#define O_F8    ((size_t)0)                        // [4] x fp8 [16384][256]: xw1,xw2,gw1,gw2
#define O_WT    (O_F8   + 4 * SZ_F8)               // bf16 [5][256][256]
#define O_XW3T  (O_WT   + (size_t)5*256*256*2)     // bf16 [4][256][4096]
#define O_XW3S  (O_XW3T + (size_t)MTOT*256*2)      // bf16 [4][256][4096]
#define O_ZX    (O_XW3S + (size_t)MTOT*256*2)      // f32 [8][16384]
#define O_ZG    (O_ZX   + (size_t)8*MTOT*4)
#define O_ID    (O_ZG   + (size_t)8*MTOT*4)        // f32 [16384]
#define O_Z2    (O_ID   + (size_t)MTOT*4)          // f32 [8][16384]
#define O_IZ2   (O_Z2   + (size_t)8*MTOT*4)        // f32 [16384]
#define O_P     (O_IZ2  + (size_t)MTOT*4)          // bf16 P, 1 or 4 batches

__device__ __forceinline__ u16 f2bf(float f) {
    u32 u = __builtin_bit_cast(u32, f);
    u32 r = (u + 0x7FFFu + ((u >> 16) & 1u)) >> 16;
    return (u16)r;
}
__device__ __forceinline__ float bf2f(u16 h) {
    u32 u = ((u32)h) << 16;
    return __builtin_bit_cast(float, u);
}
__device__ __forceinline__ f32x4 mfma_bf16(s16x8 a, s16x8 b, f32x4 c) {
    return __builtin_amdgcn_mfma_f32_16x16x32_bf16(a, b, c, 0, 0, 0);
}
__device__ __forceinline__ f32x4 mfma_fp8(long a, long b, f32x4 c) {
    return __builtin_amdgcn_mfma_f32_16x16x32_fp8_fp8(a, b, c, 0, 0, 0);
}
// XCD-contiguous remap (nwg % 8 == 0): each XCD gets a contiguous chunk.
__device__ __forceinline__ int xcd_swz(int bid, int nwg) {
    return (bid & 7) * (nwg >> 3) + (bid >> 3);
}

// ---------------------------------------------------------------------------
// prep_w: W[k][n] fp32 -> W_T[p][n][k] bf16.  grid (5,4), block 256 (t = n).
// ---------------------------------------------------------------------------
__global__ __launch_bounds__(256) void prep_w(
    const float* __restrict__ W0, const float* __restrict__ W1,
    const float* __restrict__ W2, const float* __restrict__ W3,
    const float* __restrict__ W4, u32* __restrict__ wT)
{
    const int p = blockIdx.x, kq = blockIdx.y, n = threadIdx.x;
    const float* W = (p==0)?W0:(p==1)?W1:(p==2)?W2:(p==3)?W3:W4;
#pragma unroll 4
    for (int kk = 0; kk < 32; ++kk) {
        int k = kq*64 + kk*2;
        float v0 = W[k*256 + n];
        float v1 = W[(k+1)*256 + n];
        wT[(p*65536 + n*256 + k) >> 1] = (u32)f2bf(v0) | ((u32)f2bf(v1) << 16);
    }
}

// ---------------------------------------------------------------------------
// proj: 5 projections with bf16 MFMA. grid (128, 2), block 256 (4 waves 2x2).
// ---------------------------------------------------------------------------
__global__ __launch_bounds__(256) void proj_kernel(
    const float* __restrict__ x, const float* __restrict__ g,
    const float* __restrict__ bb0, const float* __restrict__ bb1,
    const float* __restrict__ bb2, const float* __restrict__ bb3,
    const float* __restrict__ bb4,
    const u16* __restrict__ wT, u8* __restrict__ f8, u8* __restrict__ xw3T)
{
    const int branch = blockIdx.y;
    const int m0 = blockIdx.x * 128;
    const float* A = branch ? g : x;
    __shared__ u8 sA[128*512];   // bf16 [128 m][256 k], XOR-swizzled
    __shared__ u8 sC[128*512];   // bf16 bounce [128 m][256 n], XOR-swizzled
    const int t = threadIdx.x;
    const int l = t & 63, lr = l & 15, lg = l >> 4;
    const int wv = t >> 6, wm = wv >> 1, wn = wv & 1;

    { // stage A -> bf16 LDS (swizzled)
        const int m = t >> 1, h = t & 1;
        const float* src = &A[(size_t)(m0 + m) * 256 + h * 128];
        const u32 dbase = m * 512;
#pragma unroll
        for (int c = 0; c < 16; ++c) {
            float4 a = *(const float4*)(src + c*8);
            float4 b = *(const float4*)(src + c*8 + 4);
            u32 pk[4] = { (u32)f2bf(a.x) | ((u32)f2bf(a.y)<<16),
                          (u32)f2bf(a.z) | ((u32)f2bf(a.w)<<16),
                          (u32)f2bf(b.x) | ((u32)f2bf(b.y)<<16),
                          (u32)f2bf(b.z) | ((u32)f2bf(b.w)<<16) };
            int kbyte = h*256 + c*16;
            *(uint4*)&sA[dbase + (kbyte ^ ((m & 7) << 4))] = *(uint4*)pk;
        }
    }
    __syncthreads();

    const int np = branch ? 2 : 3;
    for (int pp = 0; pp < np; ++pp) {
        const int p = branch ? 3 + pp : pp;
        const float* bias = (p==0)?bb0:(p==1)?bb1:(p==2)?bb2:(p==3)?bb3:bb4;
        f32x4 acc[4][8];
#pragma unroll
        for (int i = 0; i < 4; ++i)
#pragma unroll
            for (int j = 0; j < 8; ++j) acc[i][j] = (f32x4){0.f,0.f,0.f,0.f};

#pragma unroll
        for (int ks = 0; ks < 8; ++ks) {
            s16x8 af[4];
#pragma unroll
            for (int Mt = 0; Mt < 4; ++Mt) {
                int m = wm*64 + Mt*16 + lr;
                af[Mt] = *(const s16x8*)&sA[m*512 + ((ks*64 + lg*16) ^ ((m & 7) << 4))];
            }
#pragma unroll
            for (int Nt = 0; Nt < 8; ++Nt) {
                int n = wn*128 + Nt*16 + lr;
                s16x8 bf = *(const s16x8*)&wT[p*65536 + n*256 + ks*32 + lg*8];
#pragma unroll
                for (int Mt = 0; Mt < 4; ++Mt)
                    acc[Mt][Nt] = mfma_bf16(af[Mt], bf, acc[Mt][Nt]);
            }
        }
#pragma unroll
        for (int Nt = 0; Nt < 8; ++Nt) {
            float bv = bias[wn*128 + Nt*16 + lr];
#pragma unroll
            for (int Mt = 0; Mt < 4; ++Mt)
#pragma unroll
                for (int q = 0; q < 4; ++q) acc[Mt][Nt][q] += bv;
        }

        if (p == 2) { // xw3T[b][n][pos] bf16, direct transposed stores
#pragma unroll
            for (int Mt = 0; Mt < 4; ++Mt)
#pragma unroll
                for (int Nt = 0; Nt < 8; ++Nt) {
                    int n = wn*128 + Nt*16 + lr;
                    int mrow = m0 + wm*64 + Mt*16 + lg*4;
                    int bb = mrow >> 12, pos = mrow & 4095;
                    uint2 val;
                    val.x = (u32)f2bf(acc[Mt][Nt][0]) | ((u32)f2bf(acc[Mt][Nt][1]) << 16);
                    val.y = (u32)f2bf(acc[Mt][Nt][2]) | ((u32)f2bf(acc[Mt][Nt][3]) << 16);
                    *(uint2*)(xw3T + ((size_t)(bb*256 + n)*4096 + pos)*2) = val;
                }
        } else {
            const int fi = (p < 2) ? p : p - 1;  // 0:xw1 1:xw2 2:gw1 3:gw2
#pragma unroll
            for (int Mt = 0; Mt < 4; ++Mt)
#pragma unroll
                for (int Nt = 0; Nt < 8; ++Nt) {
                    int n = wn*128 + Nt*16 + lr;
#pragma unroll
                    for (int q = 0; q < 4; ++q) {
                        int m = wm*64 + Mt*16 + lg*4 + q;
                        *(u16*)&sC[m*512 + ((n*2) ^ ((m & 7) << 4))] = f2bf(acc[Mt][Nt][q]);
                    }
                }
            __syncthreads();
            { // coalesced fp8 write-out
                const int m = t >> 1, h = t & 1;
                u8* dst = f8 + (size_t)fi * SZ_F8 + (size_t)(m0 + m)*256 + h*128;
#pragma unroll
                for (int c = 0; c < 16; ++c) {
                    uint4 v = *(const uint4*)&sC[m*512 + ((h*256 + c*16) ^ ((m & 7) << 4))];
                    float fv[8] = { bf2f((u16)(v.x & 0xffff)), bf2f((u16)(v.x >> 16)),
                                    bf2f((u16)(v.y & 0xffff)), bf2f((u16)(v.y >> 16)),
                                    bf2f((u16)(v.z & 0xffff)), bf2f((u16)(v.z >> 16)),
                                    bf2f((u16)(v.w & 0xffff)), bf2f((u16)(v.w >> 16)) };
                    u32 o0 = 0, o1 = 0;
                    o0 = __builtin_amdgcn_cvt_pk_fp8_f32(fv[0], fv[1], o0, false);
                    o0 = __builtin_amdgcn_cvt_pk_fp8_f32(fv[2], fv[3], o0, true);
                    o1 = __builtin_amdgcn_cvt_pk_fp8_f32(fv[4], fv[5], o1, false);
                    o1 = __builtin_amdgcn_cvt_pk_fp8_f32(fv[6], fv[7], o1, true);
                    uint2 ov; ov.x = o0; ov.y = o1;
                    *(uint2*)(dst + c*8) = ov;
                }
            }
            __syncthreads();
        }
    }
}

// ---------------------------------------------------------------------------
// stats1: Zx/Zg partials. 1D grid 1024 = (iblk 32, js 8, b 4), 256 thr.
// Conflict-free b64 swizzle: byte ^= (row&15)<<3  (bank = 2*((4ks+lg)^lr)).
// ---------------------------------------------------------------------------
__global__ __launch_bounds__(256, 4) void stats1_kernel(
    const u8* __restrict__ f8, float* __restrict__ ZxP, float* __restrict__ ZgP)
{
    const int sid = xcd_swz(blockIdx.x, gridDim.x);
    const int b = sid >> 8, rem = sid & 255;
    const int iblk = rem & 31, js = rem >> 5;
    const int i0 = iblk * 128;
    const int t = threadIdx.x, l = t & 63, lr = l & 15, lg = l >> 4, w = t >> 6;
    const u8* Ax = f8 + SZ_F8*1 + ((size_t)(b*NPOS + i0 + w*32))*256;
    const u8* Ag = f8 + SZ_F8*3 + ((size_t)(b*NPOS + i0 + w*32))*256;
    const u8* Bx = f8 + SZ_F8*0 + ((size_t)(b*NPOS))*256;
    const u8* Bg = f8 + SZ_F8*2 + ((size_t)(b*NPOS))*256;

    long ax[2][8], ag[2][8];
#pragma unroll
    for (int Mt = 0; Mt < 2; ++Mt)
#pragma unroll
        for (int ks = 0; ks < 8; ++ks) {
            ax[Mt][ks] = *(const long*)&Ax[(Mt*16 + lr)*256 + ks*32 + lg*8];
            ag[Mt][ks] = *(const long*)&Ag[(Mt*16 + lr)*256 + ks*32 + lg*8];
        }

    float zx[2][4], zg[2][4];
#pragma unroll
    for (int Mt = 0; Mt < 2; ++Mt)
#pragma unroll
        for (int q = 0; q < 4; ++q) { zx[Mt][q] = 0.f; zg[Mt][q] = 0.f; }

    __shared__ __attribute__((aligned(16))) u8 sb[16384];
    for (int jc = 0; jc < 16; ++jc) {
        const int j0 = js*512 + jc*32;
#pragma unroll
        for (int rep = 0; rep < 4; ++rep) {
            int s = rep*256 + t;
            int br = s >> 9, s2 = s & 511;
            int jr = s2 >> 4, kb = (s2 & 15) << 4;
            const u8* src = (br ? Bg : Bx) + (size_t)(j0 + jr)*256 + kb;
            uint4 v = *(const uint4*)src;
            int a0 = br*8192 + jr*256 + (kb ^ ((jr & 15) << 3));
            *(u64*)&sb[a0]     = ((u64)v.y << 32) | v.x;
            *(u64*)&sb[a0 ^ 8] = ((u64)v.w << 32) | v.z;
        }
        __syncthreads();
        f32x4 cx[2][2], cg[2][2];
#pragma unroll
        for (int Mt = 0; Mt < 2; ++Mt)
#pragma unroll
            for (int jt = 0; jt < 2; ++jt) { cx[Mt][jt] = (f32x4){0,0,0,0}; cg[Mt][jt] = (f32x4){0,0,0,0}; }
#pragma unroll
        for (int ks = 0; ks < 8; ++ks)
#pragma unroll
            for (int jt = 0; jt < 2; ++jt) {
                int jrow = jt*16 + lr;
                int off = jrow*256 + ((ks*32 + lg*8) ^ ((jrow & 15) << 3));
                long bxv = *(const long*)&sb[off];
                long bgv = *(const long*)&sb[8192 + off];
#pragma unroll
                for (int Mt = 0; Mt < 2; ++Mt) {
                    cx[Mt][jt] = mfma_fp8(ax[Mt][ks], bxv, cx[Mt][jt]);
                    cg[Mt][jt] = mfma_fp8(ag[Mt][ks], bgv, cg[Mt][jt]);
                }
            }
        __syncthreads();
#pragma unroll
        for (int Mt = 0; Mt < 2; ++Mt)
#pragma unroll
            for (int jt = 0; jt < 2; ++jt)
#pragma unroll
                for (int q = 0; q < 4; ++q) {
                    zx[Mt][q] += __expf(cx[Mt][jt][q]);
                    zg[Mt][q] += __expf(cg[Mt][jt][q]);
                }
    }
#pragma unroll
    for (int Mt = 0; Mt < 2; ++Mt)
#pragma unroll
        for (int q = 0; q < 4; ++q)
#pragma unroll
            for (int o = 1; o < 16; o <<= 1) {
                zx[Mt][q] += __shfl_xor(zx[Mt][q], o, 64);
                zg[Mt][q] += __shfl_xor(zg[Mt][q], o, 64);
            }
    if (lr == 0) {
#pragma unroll
        for (int Mt = 0; Mt < 2; ++Mt)
#pragma unroll
            for (int q = 0; q < 4; ++q) {
                int gi = b*NPOS + i0 + w*32 + Mt*16 + lg*4 + q;
                ZxP[js*MTOT + gi] = zx[Mt][q];
                ZgP[js*MTOT + gi] = zg[Mt][q];
            }
    }
}

// ---------------------------------------------------------------------------
__global__ __launch_bounds__(256) void merge_d(
    const float* __restrict__ ZxP, const float* __restrict__ ZgP,
    float* __restrict__ iD)
{
    int gi = blockIdx.x*256 + threadIdx.x;
    float zx = 0.f, zg = 0.f;
#pragma unroll
    for (int js = 0; js < 8; ++js) { zx += ZxP[js*MTOT + gi]; zg += ZgP[js*MTOT + gi]; }
    iD[gi] = 1.0f / (zx * zg);
}

// ---------------------------------------------------------------------------
// stats2: P^T[j][i] = exp( exp(Sx+Sg) * iD_i ) bf16 (LDS-bounced, coalesced),
// plus z2 partials. 1D grid 256*nb = (iblk 32, js 8, batch), 256 thr.
// ---------------------------------------------------------------------------
__global__ __launch_bounds__(256, 3) void stats2_kernel(
    const u8* __restrict__ f8, const float* __restrict__ iD,
    float* __restrict__ z2P, u8* __restrict__ PT, int bbase, int big)
{
    const int sid = xcd_swz(blockIdx.x, gridDim.x);
    const int bz = sid >> 8, rem = sid & 255;
    const int batch = bbase + bz;
    const int iblk = rem & 31, js = rem >> 5;
    const int i0 = iblk * 128;
    const int t = threadIdx.x, l = t & 63, lr = l & 15, lg = l >> 4, w = t >> 6;
    const u8* Ax = f8 + SZ_F8*1 + ((size_t)(batch*NPOS + i0 + w*32))*256;
    const u8* Ag = f8 + SZ_F8*3 + ((size_t)(batch*NPOS + i0 + w*32))*256;
    const u8* Bx = f8 + SZ_F8*0 + ((size_t)(batch*NPOS))*256;
    const u8* Bg = f8 + SZ_F8*2 + ((size_t)(batch*NPOS))*256;
    u8* PTb = PT + (big ? (size_t)bz * PBYTES : 0);

    long ax[2][8], ag[2][8];
#pragma unroll
    for (int Mt = 0; Mt < 2; ++Mt)
#pragma unroll
        for (int ks = 0; ks < 8; ++ks) {
            ax[Mt][ks] = *(const long*)&Ax[(Mt*16 + lr)*256 + ks*32 + lg*8];
            ag[Mt][ks] = *(const long*)&Ag[(Mt*16 + lr)*256 + ks*32 + lg*8];
        }
    f32x4 iDv[2];
#pragma unroll
    for (int Mt = 0; Mt < 2; ++Mt)
        iDv[Mt] = *(const f32x4*)&iD[batch*NPOS + i0 + w*32 + Mt*16 + lg*4];

    float z2a[2][4];
#pragma unroll
    for (int Mt = 0; Mt < 2; ++Mt)
#pragma unroll
        for (int q = 0; q < 4; ++q) z2a[Mt][q] = 0.f;

    __shared__ __attribute__((aligned(16))) u8 sb[16384];
    __shared__ __attribute__((aligned(16))) u8 pb[8192];   // [32 j][128 i] bf16 bounce
    for (int jc = 0; jc < 16; ++jc) {
        const int j0 = js*512 + jc*32;
#pragma unroll
        for (int rep = 0; rep < 4; ++rep) {
            int s = rep*256 + t;
            int br = s >> 9, s2 = s & 511;
            int jr = s2 >> 4, kb = (s2 & 15) << 4;
            const u8* src = (br ? Bg : Bx) + (size_t)(j0 + jr)*256 + kb;
            uint4 v = *(const uint4*)src;
            int a0 = br*8192 + jr*256 + (kb ^ ((jr & 15) << 3));
            *(u64*)&sb[a0]     = ((u64)v.y << 32) | v.x;
            *(u64*)&sb[a0 ^ 8] = ((u64)v.w << 32) | v.z;
        }
        __syncthreads();
        f32x4 cx[2][2], cg[2][2];
#pragma unroll
        for (int Mt = 0; Mt < 2; ++Mt)
#pragma unroll
            for (int jt = 0; jt < 2; ++jt) { cx[Mt][jt] = (f32x4){0,0,0,0}; cg[Mt][jt] = (f32x4){0,0,0,0}; }
#pragma unroll
        for (int ks = 0; ks < 8; ++ks)
#pragma unroll
            for (int jt = 0; jt < 2; ++jt) {
                int jrow = jt*16 + lr;
                int off = jrow*256 + ((ks*32 + lg*8) ^ ((jrow & 15) << 3));
                long bxv = *(const long*)&sb[off];
                long bgv = *(const long*)&sb[8192 + off];
#pragma unroll
                for (int Mt = 0; Mt < 2; ++Mt) {
                    cx[Mt][jt] = mfma_fp8(ax[Mt][ks], bxv, cx[Mt][jt]);
                    cg[Mt][jt] = mfma_fp8(ag[Mt][ks], bgv, cg[Mt][jt]);
                }
            }
        // P -> LDS bounce (swizzled u64 writes)
#pragma unroll
        for (int Mt = 0; Mt < 2; ++Mt)
#pragma unroll
            for (int jt = 0; jt < 2; ++jt) {
                int jl = jt*16 + lr;
                float e[4];
#pragma unroll
                for (int q = 0; q < 4; ++q) {
                    float T = cx[Mt][jt][q] + cg[Mt][jt][q];
                    float v = __expf(T) * iDv[Mt][q];
                    e[q] = __expf(v);
                    z2a[Mt][q] += e[q];
                }
                u64 pk = (u64)((u32)f2bf(e[0]) | ((u32)f2bf(e[1]) << 16)) |
                         ((u64)((u32)f2bf(e[2]) | ((u32)f2bf(e[3]) << 16)) << 32);
                int ioff = w*64 + Mt*32 + lg*8;
                *(u64*)&pb[jl*256 + (ioff ^ ((jl & 15) << 3))] = pk;
            }
        __syncthreads();
        { // coalesced PT store: 32 rows x 256 B
            const int row = t >> 3, seg = t & 7;
            const int swz = (row & 15) << 3;
            u8* dst = PTb + (size_t)(j0 + row)*8192 + (size_t)i0*2 + seg*32;
#pragma unroll
            for (int h = 0; h < 2; ++h) {
                int a0 = row*256 + ((seg*32 + h*16) ^ swz);
                u64 lo = *(const u64*)&pb[a0];
                u64 hi = *(const u64*)&pb[a0 ^ 8];
                uint4 o; o.x = (u32)lo; o.y = (u32)(lo >> 32);
                o.z = (u32)hi; o.w = (u32)(hi >> 32);
                *(uint4*)(dst + h*16) = o;
            }
        }
        __syncthreads();
    }
#pragma unroll
    for (int Mt = 0; Mt < 2; ++Mt)
#pragma unroll
        for (int q = 0; q < 4; ++q)
#pragma unroll
            for (int o = 1; o < 16; o <<= 1)
                z2a[Mt][q] += __shfl_xor(z2a[Mt][q], o, 64);
    if (lr == 0) {
#pragma unroll
        for (int Mt = 0; Mt < 2; ++Mt)
#pragma unroll
            for (int q = 0; q < 4; ++q) {
                int gi = batch*NPOS + i0 + w*32 + Mt*16 + lg*4 + q;
                z2P[js*MTOT + gi] = z2a[Mt][q];
            }
    }
}

// ---------------------------------------------------------------------------
__global__ __launch_bounds__(256) void prep_iz2(
    const float* __restrict__ z2P, float* __restrict__ iZ2, int bbase)
{
    int gi = bbase*NPOS + blockIdx.x*256 + threadIdx.x;
    float s = 0.f;
#pragma unroll
    for (int js = 0; js < 8; ++js) s += z2P[js*MTOT + gi];
    iZ2[gi] = 1.0f / s;
}

// xw3s[b][c][i] = xw3T[b][c][i] * iZ2[b*4096+i]   (bf16)
__global__ __launch_bounds__(256) void scalev(
    const u8* __restrict__ xw3T, const float* __restrict__ iZ2,
    u8* __restrict__ xw3s, int bbase)
{
    int eg = blockIdx.x*256 + threadIdx.x;
    int bz = bbase + (eg >> 17);
    int rem = eg & 131071;
    int c = rem >> 9, i = (rem & 511) << 3;
    size_t off = ((size_t)(bz*256 + c)*4096 + i)*2;
    uint4 v = *(const uint4*)(xw3T + off);
    f32x4 z0 = *(const f32x4*)&iZ2[bz*NPOS + i];
    f32x4 z1 = *(const f32x4*)&iZ2[bz*NPOS + i + 4];
    uint4 r;
    r.x = (u32)f2bf(bf2f((u16)(v.x & 0xffff))*z0[0]) | ((u32)f2bf(bf2f((u16)(v.x >> 16))*z0[1]) << 16);
    r.y = (u32)f2bf(bf2f((u16)(v.y & 0xffff))*z0[2]) | ((u32)f2bf(bf2f((u16)(v.y >> 16))*z0[3]) << 16);
    r.z = (u32)f2bf(bf2f((u16)(v.z & 0xffff))*z1[0]) | ((u32)f2bf(bf2f((u16)(v.z >> 16))*z1[1]) << 16);
    r.w = (u32)f2bf(bf2f((u16)(v.w & 0xffff))*z1[2]) | ((u32)f2bf(bf2f((u16)(v.w >> 16))*z1[3]) << 16);
    *(uint4*)(xw3s + off) = r;
}

// ---------------------------------------------------------------------------
// pv: out[b][j][c] = x[b][j][c] + sum_i PT[j,i] * xw3s[c,i]   (NT bf16 GEMM)
// 1D grid 256*nb = (jb 64, cb 4, batch), 256 thr (4 waves 2x2, wave 32x32).
// ---------------------------------------------------------------------------
__global__ __launch_bounds__(256, 4) void pv_kernel(
    const u8* __restrict__ PT, const u8* __restrict__ xw3s,
    const float* __restrict__ x, float* __restrict__ out, int bbase, int big)
{
    const int sid = xcd_swz(blockIdx.x, gridDim.x);
    const int bz = sid >> 8, rem = sid & 255;
    const int batch = bbase + bz;
    const int j0 = (rem & 63) * 64, c0 = (rem >> 6) * 64;
    const u8* PTb = PT + (big ? (size_t)bz * PBYTES : 0);
    __shared__ __attribute__((aligned(16))) u8 sA[8192], sB[8192];  // bf16 [64][64]
    const int t = threadIdx.x, l = t & 63, lr = l & 15, lg = l >> 4;
    const int wv = t >> 6, wm = wv >> 1, wn = wv & 1;

    f32x4 acc[2][2];
#pragma unroll
    for (int Mt = 0; Mt < 2; ++Mt)
#pragma unroll
        for (int Nt = 0; Nt < 2; ++Nt) acc[Mt][Nt] = (f32x4){0,0,0,0};

    for (int kt = 0; kt < 64; ++kt) {
        const int k0 = kt * 64;
#pragma unroll
        for (int rep = 0; rep < 4; ++rep) {
            int s = rep*256 + t;
            int buf = s >> 9, s2 = s & 511;
            int row = s2 >> 3, seg = s2 & 7;
            const u8* src = buf
                ? xw3s + ((size_t)(batch*256 + c0 + row)*4096 + k0)*2 + seg*16
                : PTb  + ((size_t)(j0 + row)*4096 + k0)*2 + seg*16;
            u8* dst = (buf ? sB : sA) + row*128 + ((seg*16) ^ ((row & 7) << 4));
            *(uint4*)dst = *(const uint4*)src;
        }
        __syncthreads();
#pragma unroll
        for (int ks = 0; ks < 2; ++ks) {
            s16x8 af[2], bf[2];
#pragma unroll
            for (int Mt = 0; Mt < 2; ++Mt) {
                int row = wm*32 + Mt*16 + lr;
                af[Mt] = *(const s16x8*)&sA[row*128 + ((ks*64 + lg*16) ^ ((row & 7) << 4))];
            }
#pragma unroll
            for (int Nt = 0; Nt < 2; ++Nt) {
                int row = wn*32 + Nt*16 + lr;
                bf[Nt] = *(const s16x8*)&sB[row*128 + ((ks*64 + lg*16) ^ ((row & 7) << 4))];
            }
#pragma unroll
            for (int Mt = 0; Mt < 2; ++Mt)
#pragma unroll
                for (int Nt = 0; Nt < 2; ++Nt)
                    acc[Mt][Nt] = mfma_bf16(af[Mt], bf[Nt], acc[Mt][Nt]);
        }
        __syncthreads();
    }
#pragma unroll
    for (int Mt = 0; Mt < 2; ++Mt)
#pragma unroll
        for (int Nt = 0; Nt < 2; ++Nt)
#pragma unroll
            for (int q = 0; q < 4; ++q) {
                int j = j0 + wm*32 + Mt*16 + lg*4 + q;
                int c = c0 + wn*32 + Nt*16 + lr;
                size_t idx = ((size_t)(batch*NPOS + j))*256 + c;
                out[idx] = x[idx] + acc[Mt][Nt][q];
            }
}

// ---------------------------------------------------------------------------
extern "C" void kernel_launch(void* const* d_in, const int* in_sizes, int n_in,
                              void* d_out, int out_size, void* d_ws, size_t ws_size,
                              hipStream_t stream)
{
    const float* x = (const float*)d_in[0];
    const float* g = (const float*)d_in[1];
    const float* W[5]  = {(const float*)d_in[2], (const float*)d_in[4], (const float*)d_in[6],
                          (const float*)d_in[8], (const float*)d_in[10]};
    const float* Bi[5] = {(const float*)d_in[3], (const float*)d_in[5], (const float*)d_in[7],
                          (const float*)d_in[9], (const float*)d_in[11]};
    char* ws = (char*)d_ws;
    u8*  f8   = (u8*)(ws + O_F8);
    u16* wT   = (u16*)(ws + O_WT);
    u8*  xw3T = (u8*)(ws + O_XW3T);
    u8*  xw3s = (u8*)(ws + O_XW3S);
    float* ZxP = (float*)(ws + O_ZX);
    float* ZgP = (float*)(ws + O_ZG);
    float* iD  = (float*)(ws + O_ID);
    float* z2P = (float*)(ws + O_Z2);
    float* iZ2 = (float*)(ws + O_IZ2);
    u8*  PT   = (u8*)(ws + O_P);
    float* out = (float*)d_out;

    const int big = (ws_size >= O_P + 4 * PBYTES) ? 1 : 0;

    prep_w<<<dim3(5,4), 256, 0, stream>>>(W[0], W[1], W[2], W[3], W[4], (u32*)wT);
    proj_kernel<<<dim3(128,2), 256, 0, stream>>>(x, g, Bi[0], Bi[1], Bi[2], Bi[3], Bi[4],
                                                 wT, f8, xw3T);
    stats1_kernel<<<1024, 256, 0, stream>>>(f8, ZxP, ZgP);
    merge_d<<<64, 256, 0, stream>>>(ZxP, ZgP, iD);
    if (big) {
        stats2_kernel<<<1024, 256, 0, stream>>>(f8, iD, z2P, PT, 0, 1);
        prep_iz2<<<64, 256, 0, stream>>>(z2P, iZ2, 0);
        scalev<<<2048, 256, 0, stream>>>(xw3T, iZ2, xw3s, 0);
        pv_kernel<<<1024, 256, 0, stream>>>(PT, xw3s, x, out, 0, 1);
    } else {
        for (int b = 0; b < 4; ++b) {
            stats2_kernel<<<256, 256, 0, stream>>>(f8, iD, z2P, PT, b, 0);
            prep_iz2<<<16, 256, 0, stream>>>(z2P, iZ2, b);
            scalev<<<512, 256, 0, stream>>>(xw3T, iZ2, xw3s, b);
            pv_kernel<<<256, 256, 0, stream>>>(PT, xw3s, x, out, b, 0);
        }
    }
}